// Round 4
// baseline (230.028 us; speedup 1.0000x reference)
//
#include <hip/hip_runtime.h>

// SAdapter fused kernel v4: one block per image (B=2048), 256 threads.
// v3 structure with the reshape-semantics fix in the fused C2+D phase:
// y row n2 consumes z_hist FLAT elements [n2*8 .. n2*8+7] of (c*196+hw) order.
// LDS 18.4 KB, 2 barriers, target 8 blocks/CU.

#define DIMD 192

__launch_bounds__(256, 8)
__global__ void sadapter_kernel(
    const float* __restrict__ x,
    const float* __restrict__ W1,
    const float* __restrict__ b1,
    const float* __restrict__ conv1_w,
    const float* __restrict__ conv1_b,
    const float* __restrict__ cdc_w,
    const float* __restrict__ wc1,
    const float* __restrict__ wc2,
    const float* __restrict__ hist_w,
    const float* __restrict__ hist_b,
    float* __restrict__ out)
{
    __shared__ float smem[4608];   // 18432 B
    float* TS  = smem;             // [8][16][16] padded t  (border 0)
    float* PS  = smem + 2048;      // [8][16][16] padded P  (border 1)
    float* WB2 = smem + 4096;      // [64][8] packed small weights

    const int tid = threadIdx.x;
    const float* xb   = x   + (size_t)blockIdx.x * (197 * DIMD);
    float*       outb = out + (size_t)blockIdx.x * (197 * DIMD);

    // ---- Phase 0: init borders, pack weights ----
    {
        float4 z4 = make_float4(0.f, 0.f, 0.f, 0.f);
        float4 o4 = make_float4(1.f, 1.f, 1.f, 1.f);
        ((float4*)TS)[tid]       = z4;
        ((float4*)TS)[tid + 256] = z4;
        ((float4*)PS)[tid]       = o4;
        ((float4*)PS)[tid + 256] = o4;
    }
    if (tid < 64) {
        // tid = o*8+i ; cdc_w (8,8,1,5)
        const float* c5 = cdc_w + tid * 5;
        float k0 = c5[0], k1 = c5[1], k2 = c5[2], k3 = c5[3], k4 = c5[4];
        float kd = k0 + k1 + k2 + k3 + k4;
        float* wp = WB2 + tid * 8;
        wp[0] = conv1_w[tid] + k2 - 0.7f * kd;  // center: 1x1 + cdc-center - theta*diff
        wp[1] = k0;  // up
        wp[2] = k1;  // left
        wp[3] = k3;  // right
        wp[4] = k4;  // down
        wp[5] = wc1[tid];
        wp[6] = wc2[tid];
        wp[7] = 0.f;
    }
    __syncthreads();

    // ---- Phase A: t[n,c] = tok[n,:] @ W1[c,:] + b1[c] ----
    if (tid < 196) {
        const float4* rowp = (const float4*)(xb + DIMD + tid * DIMD);
        float acc[8];
        #pragma unroll
        for (int c = 0; c < 8; ++c) acc[c] = b1[c];          // uniform -> s_load
        #pragma unroll
        for (int blk = 0; blk < 6; ++blk) {                  // 6 batches of 32 d
            float4 tv[8];
            #pragma unroll
            for (int u = 0; u < 8; ++u) tv[u] = rowp[blk * 8 + u];
            #pragma unroll
            for (int c = 0; c < 8; ++c) {
                const float* wrow = W1 + c * DIMD + blk * 32; // 32 contiguous, uniform
                #pragma unroll
                for (int u = 0; u < 8; ++u) {
                    acc[c] += tv[u].x * wrow[u * 4 + 0] + tv[u].y * wrow[u * 4 + 1]
                            + tv[u].z * wrow[u * 4 + 2] + tv[u].w * wrow[u * 4 + 3];
                }
            }
        }
        int h = tid / 14, w = tid - h * 14;
        float* tp = TS + (h + 1) * 16 + (w + 1);
        #pragma unroll
        for (int c = 0; c < 8; ++c) tp[c * 256] = acc[c];
    } else {
        int f = tid - 196;                                    // class token copy
        if (f < 48) ((float4*)outb)[f] = ((const float4*)xb)[f];
    }
    __syncthreads();

    // ---- Phase BC: z_star in regs -> mu/gamma -> P = exp(-(g*(z-mu))^2) ----
    if (tid < 196) {
        int h = tid / 14, w = tid - h * 14;
        const float* tp = TS + (h + 1) * 16 + (w + 1);
        float zv[8];
        #pragma unroll
        for (int c = 0; c < 8; ++c) zv[c] = conv1_b[c];       // uniform -> s_load
        #pragma unroll
        for (int i = 0; i < 8; ++i) {
            float t0 = tp[i * 256];
            float tu = tp[i * 256 - 16];
            float td = tp[i * 256 + 16];
            float tl = tp[i * 256 - 1];
            float tr = tp[i * 256 + 1];
            #pragma unroll
            for (int c = 0; c < 8; ++c) {
                const float* wp = WB2 + (c * 8 + i) * 8;      // broadcast b128 + b32
                float4 wv = *(const float4*)wp;
                float wd = wp[4];
                zv[c] += wv.x * t0 + wv.y * tu + wv.z * tl + wv.w * tr + wd * td;
            }
        }
        float* pp = PS + (h + 1) * 16 + (w + 1);
        #pragma unroll
        for (int c = 0; c < 8; ++c) {
            float mu = 0.f, ga = 0.f;
            #pragma unroll
            for (int i = 0; i < 8; ++i) {
                const float* wp = WB2 + (c * 8 + i) * 8;
                mu += wp[5] * zv[i];
                ga += wp[6] * zv[i];
            }
            float e = ga * (zv[c] - mu);
            pp[c * 256] = __expf(-e * e);
        }
    }
    __syncthreads();

    // ---- Phase C2+D fused: z_hist FLAT elements [tid*8 .. tid*8+7] -> y row tid ----
    if (tid < 196) {
        float zr[8];
        {
            int f  = tid * 8;
            int c  = f / 196;          // channel of flat index
            int hw = f - c * 196;
            int h  = hw / 14;
            int w  = hw - h * 14;
            #pragma unroll
            for (int c2 = 0; c2 < 8; ++c2) {
                // 3x3 box sum over padded P, centered at (h+1, w+1), channel c
                const float* pr = PS + c * 256 + h * 16 + w;
                float s9 = pr[0]  + pr[1]  + pr[2]
                         + pr[16] + pr[17] + pr[18]
                         + pr[32] + pr[33] + pr[34];
                zr[c2] = s9 * (1.f / 9.f);
                // advance flat index by 1: w++, wrap w->h->c
                ++w;
                if (w == 14) { w = 0; ++h; }
                if (h == 14) { h = 0; ++c; }
            }
        }
        float4* oy = (float4*)(outb + DIMD + tid * DIMD);
        #pragma unroll 2
        for (int d4 = 0; d4 < 48; ++d4) {
            const float* hw_ = hist_w + d4 * 32;              // 32 contiguous, uniform
            const float* hb  = hist_b + d4 * 4;               // uniform
            float4 a = make_float4(hb[0], hb[1], hb[2], hb[3]);
            #pragma unroll
            for (int c2 = 0; c2 < 8; ++c2) {
                float s = zr[c2];
                a.x += s * hw_[0 * 8 + c2];
                a.y += s * hw_[1 * 8 + c2];
                a.z += s * hw_[2 * 8 + c2];
                a.w += s * hw_[3 * 8 + c2];
            }
            oy[d4] = a;
        }
    }
}

extern "C" void kernel_launch(void* const* d_in, const int* in_sizes, int n_in,
                              void* d_out, int out_size, void* d_ws, size_t ws_size,
                              hipStream_t stream)
{
    const float* x       = (const float*)d_in[0];
    const float* W1      = (const float*)d_in[1];
    const float* b1      = (const float*)d_in[2];
    const float* conv1_w = (const float*)d_in[3];
    const float* conv1_b = (const float*)d_in[4];
    const float* cdc_w   = (const float*)d_in[5];
    const float* wc1     = (const float*)d_in[6];
    const float* wc2     = (const float*)d_in[7];
    const float* hist_w  = (const float*)d_in[8];
    const float* hist_b  = (const float*)d_in[9];
    float* out = (float*)d_out;

    sadapter_kernel<<<2048, 256, 0, stream>>>(
        x, W1, b1, conv1_w, conv1_b, cdc_w, wc1, wc2, hist_w, hist_b, out);
}